// Round 6
// baseline (971.322 us; speedup 1.0000x reference)
//
#include <hip/hip_runtime.h>
#include <math.h>

// Problem constants
#define B_   128
#define IN_  1024
#define OUT_ 1024
#define E_   32

// moe_main tiling
#define SLAB  64                 // i-rows per block
#define NSLAB (IN_ / SLAB)       // 16
#define CHR   8                  // rows per LDS chunk (32 KB)
#define NCH   (SLAB / CHR)       // 8
#define S_    16                 // samples per group pass
#define THR   512

// ---------------- Kernel A: routing, one block per (sample, router) --------------
// route layout: route[(b*2 + r)*4] = [idx0, idx1, p0, p1]  (idx bit-cast)
__global__ __launch_bounds__(256) void route_kernel(
    const float* __restrict__ x, const float* __restrict__ rw,
    const float* __restrict__ brw, float* __restrict__ route) {
  int b = blockIdx.x;
  int r = blockIdx.y;
  int t = threadIdx.x;
  const float* w = r ? brw : rw;

  __shared__ float xs[IN_];
  __shared__ float part[8][E_];
  __shared__ float lg[E_];

  ((float4*)xs)[t] = ((const float4*)(x + (size_t)b * IN_))[t];
  __syncthreads();

  int e  = t & 31;
  int ic = t >> 5;
  int base = ic * 128;
  float acc = 0.f;
  #pragma unroll 8
  for (int i = 0; i < 128; ++i)
    acc += xs[base + i] * w[(size_t)(base + i) * E_ + e];
  part[ic][e] = acc;
  __syncthreads();

  if (t < E_) {
    float s = 0.f;
    #pragma unroll
    for (int q = 0; q < 8; ++q) s += part[q][t];
    lg[t] = s;
  }
  __syncthreads();

  if (t == 0) {
    int bi0 = -1, bi1 = -1;
    float v0 = -INFINITY, v1 = -INFINITY;
    for (int ee = 0; ee < E_; ++ee) {
      float v = lg[ee];
      if (v > v0) { v1 = v0; bi1 = bi0; v0 = v; bi0 = ee; }
      else if (v > v1) { v1 = v; bi1 = ee; }
    }
    float p0 = 1.f / (1.f + expf(v1 - v0));
    float* rp = route + ((size_t)b * 2 + r) * 4;
    rp[0] = __int_as_float(bi0);
    rp[1] = __int_as_float(bi1);
    rp[2] = p0;
    rp[3] = 1.f - p0;
  }
}

// ---------------- Kernel A2: per-expert sample lists (deterministic scan) --------
__global__ __launch_bounds__(128) void build_lists(
    const float* __restrict__ route, int* __restrict__ counts,
    int* __restrict__ list_b, float* __restrict__ list_p) {
  __shared__ float4 r_sh[B_];
  int t = threadIdx.x;  // 128
  r_sh[t] = *(const float4*)(route + (size_t)t * 8);  // router-0 entry of sample t
  __syncthreads();
  if (t < E_) {
    int c = 0;
    for (int b = 0; b < B_; ++b) {
      float4 r = r_sh[b];
      int i0 = __float_as_int(r.x);
      int i1 = __float_as_int(r.y);
      if (i0 == t)      { list_b[t * B_ + c] = b; list_p[t * B_ + c] = r.z; ++c; }
      else if (i1 == t) { list_b[t * B_ + c] = b; list_p[t * B_ + c] = r.w; ++c; }
    }
    counts[t] = c;
  }
}

// ---------------- Kernel B: bias init: out[b] = pb0*eb[ib0] + pb1*eb[ib1] --------
__global__ __launch_bounds__(256) void bias_init(
    const float* __restrict__ route, const float* __restrict__ eb,
    float* __restrict__ out) {
  int b = blockIdx.x;
  int t = threadIdx.x;
  const float* rp = route + ((size_t)b * 2 + 1) * 4;
  int ib0 = __float_as_int(rp[0]);
  int ib1 = __float_as_int(rp[1]);
  float pb0 = rp[2], pb1 = rp[3];
  float4 b0 = ((const float4*)(eb + (size_t)ib0 * OUT_))[t];
  float4 b1 = ((const float4*)(eb + (size_t)ib1 * OUT_))[t];
  float4 o;
  o.x = pb0 * b0.x + pb1 * b1.x;
  o.y = pb0 * b0.y + pb1 * b1.y;
  o.z = pb0 * b0.z + pb1 * b1.z;
  o.w = pb0 * b0.w + pb1 * b1.w;
  ((float4*)(out + (size_t)b * OUT_))[t] = o;
}

// ---------------- Kernel C: linear-streamed expert matvecs ----------------
// block = (e, slab of 64 i-rows). The block streams its 256 KB weight slab
// CONTIGUOUSLY (stride-16B across lanes, chunks of 32 KB) through a
// double-buffered LDS tile: loads for chunk k+1 issue to regs before the
// compute of chunk k (T14 issue-early / write-late), one barrier per chunk.
// Thread owns 2 output cols x 16 samples (acc fully static, 32 VGPR).
__global__ __launch_bounds__(THR) void moe_main(
    const float* __restrict__ x, const float* __restrict__ ew,
    const int* __restrict__ counts, const int* __restrict__ list_b,
    const float* __restrict__ list_p, float* __restrict__ out) {
  int e    = blockIdx.x;
  int slab = blockIdx.y;
  int c = counts[e];
  if (c == 0) return;

  __shared__ float wbuf[2][CHR * OUT_];   // 2 x 32 KB
  __shared__ float xs[SLAB][S_];          // 4 KB, xs[i][s], rows 64B-aligned
  __shared__ int   bs[S_];
  __shared__ float ps[S_];

  int t  = threadIdx.x;
  int i0 = slab * SLAB;
  const float* wslab = ew + ((size_t)e * IN_ + i0) * OUT_;

  for (int g0 = 0; g0 < c; g0 += S_) {
    __syncthreads();   // previous pass's bs/ps/xs readers done
    if (t < S_) {
      int idx = g0 + t;
      int cidx = min(idx, c - 1);
      bs[t] = list_b[e * B_ + cidx];
      ps[t] = (idx < c) ? list_p[e * B_ + cidx] : 0.f;
    }
    // issue chunk-0 weight loads (independent of bs)
    float4 st0, st1, st2, st3;
    {
      const float4* g = (const float4*)wslab;
      st0 = g[t]; st1 = g[t + THR]; st2 = g[t + 2 * THR]; st3 = g[t + 3 * THR];
    }
    __syncthreads();   // bs/ps visible

    // stage x transposed: thread t -> (s = t&15, i-pair = t>>4)
    {
      int s  = t & 15;
      int ip = t >> 4;                    // 0..31
      const float* xr = x + (size_t)bs[s] * IN_ + i0 + 2 * ip;
      float2 v = *(const float2*)xr;
      xs[2 * ip][s]     = v.x;
      xs[2 * ip + 1][s] = v.y;
    }
    // write chunk 0 (compiler waits vmcnt for st regs here)
    ((float4*)wbuf[0])[t]           = st0;
    ((float4*)wbuf[0])[t + THR]     = st1;
    ((float4*)wbuf[0])[t + 2*THR]   = st2;
    ((float4*)wbuf[0])[t + 3*THR]   = st3;
    __syncthreads();   // chunk0 + xs visible

    float2 acc[S_];
    #pragma unroll
    for (int s = 0; s < S_; ++s) acc[s] = make_float2(0.f, 0.f);

    #pragma unroll
    for (int ch = 0; ch < NCH; ++ch) {
      // issue next chunk's loads early (hidden under this chunk's compute)
      if (ch + 1 < NCH) {
        const float4* g = (const float4*)(wslab + (size_t)(ch + 1) * CHR * OUT_);
        st0 = g[t]; st1 = g[t + THR]; st2 = g[t + 2 * THR]; st3 = g[t + 3 * THR];
      }
      // compute current chunk from LDS
      const float* wl = wbuf[ch & 1];
      #pragma unroll
      for (int k = 0; k < CHR; ++k) {
        int i = ch * CHR + k;
        float2 wv = *(const float2*)(wl + k * OUT_ + t * 2);
        const float4* xr = (const float4*)xs[i];
        float4 x0 = xr[0], x1 = xr[1], x2 = xr[2], x3 = xr[3];
        const float xf[S_] = {x0.x, x0.y, x0.z, x0.w, x1.x, x1.y, x1.z, x1.w,
                              x2.x, x2.y, x2.z, x2.w, x3.x, x3.y, x3.z, x3.w};
        #pragma unroll
        for (int s = 0; s < S_; ++s) {
          acc[s].x += xf[s] * wv.x;
          acc[s].y += xf[s] * wv.y;
        }
      }
      // write next chunk into the other buffer (prev readers of it passed
      // the barrier at the end of iteration ch-1)
      if (ch + 1 < NCH) {
        float* wb = wbuf[(ch + 1) & 1];
        ((float4*)wb)[t]          = st0;
        ((float4*)wb)[t + THR]    = st1;
        ((float4*)wb)[t + 2*THR]  = st2;
        ((float4*)wb)[t + 3*THR]  = st3;
      }
      __syncthreads();
    }

    // epilogue: one atomic contribution per (sample, col) for this slab
    #pragma unroll
    for (int s = 0; s < S_; ++s) {
      if (g0 + s < c) {
        float p = ps[s];
        float* op = out + (size_t)bs[s] * OUT_ + t * 2;
        atomicAdd(op + 0, p * acc[s].x);
        atomicAdd(op + 1, p * acc[s].y);
      }
    }
  }
}

extern "C" void kernel_launch(void* const* d_in, const int* in_sizes, int n_in,
                              void* d_out, int out_size, void* d_ws, size_t ws_size,
                              hipStream_t stream) {
  const float* x   = (const float*)d_in[0];
  const float* rw  = (const float*)d_in[1];
  const float* brw = (const float*)d_in[2];
  const float* ew  = (const float*)d_in[3];
  const float* eb  = (const float*)d_in[4];
  float* out = (float*)d_out;

  float* route  = (float*)d_ws;                                   // 128*2*4 floats = 4 KB
  int*   counts = (int*)((char*)d_ws + 4096);                     // 32 ints
  int*   list_b = (int*)((char*)d_ws + 4096 + 128);               // 32*128 ints
  float* list_p = (float*)((char*)d_ws + 4096 + 128 + 16384);     // 32*128 floats

  route_kernel<<<dim3(B_, 2), 256, 0, stream>>>(x, rw, brw, route);
  build_lists<<<1, 128, 0, stream>>>(route, counts, list_b, list_p);
  bias_init<<<B_, 256, 0, stream>>>(route, eb, out);
  moe_main<<<dim3(E_, NSLAB), THR, 0, stream>>>(x, ew, counts, list_b, list_p, out);
}

// Round 7
// 85.105 us; speedup vs baseline: 11.4133x; 11.4133x over previous
//
#include <hip/hip_runtime.h>
#include <math.h>

// Problem constants
#define B_   128
#define IN_  1024
#define OUT_ 1024
#define E_   32

// moe_main tiling
#define SLAB  64                 // i-rows per block
#define NSLAB (IN_ / SLAB)       // 16
#define S_    16                 // samples per group pass
#define RB    4                  // rows per prefetch batch
#define THR   512

// ---------------- Kernel A: routing, one block per (sample, router) --------------
// route layout: route[(b*2 + r)*4] = [idx0, idx1, p0, p1]  (idx bit-cast)
__global__ __launch_bounds__(256) void route_kernel(
    const float* __restrict__ x, const float* __restrict__ rw,
    const float* __restrict__ brw, float* __restrict__ route) {
  int b = blockIdx.x;
  int r = blockIdx.y;
  int t = threadIdx.x;
  const float* w = r ? brw : rw;

  __shared__ float xs[IN_];
  __shared__ float part[8][E_];
  __shared__ float lg[E_];

  ((float4*)xs)[t] = ((const float4*)(x + (size_t)b * IN_))[t];
  __syncthreads();

  int e  = t & 31;
  int ic = t >> 5;
  int base = ic * 128;
  float acc = 0.f;
  #pragma unroll 8
  for (int i = 0; i < 128; ++i)
    acc += xs[base + i] * w[(size_t)(base + i) * E_ + e];
  part[ic][e] = acc;
  __syncthreads();

  if (t < E_) {
    float s = 0.f;
    #pragma unroll
    for (int q = 0; q < 8; ++q) s += part[q][t];
    lg[t] = s;
  }
  __syncthreads();

  if (t == 0) {
    int bi0 = -1, bi1 = -1;
    float v0 = -INFINITY, v1 = -INFINITY;
    for (int ee = 0; ee < E_; ++ee) {
      float v = lg[ee];
      if (v > v0) { v1 = v0; bi1 = bi0; v0 = v; bi0 = ee; }
      else if (v > v1) { v1 = v; bi1 = ee; }
    }
    float p0 = 1.f / (1.f + expf(v1 - v0));
    float* rp = route + ((size_t)b * 2 + r) * 4;
    rp[0] = __int_as_float(bi0);
    rp[1] = __int_as_float(bi1);
    rp[2] = p0;
    rp[3] = 1.f - p0;
  }
}

// ---------------- Kernel A2: per-expert sample lists (deterministic scan) --------
__global__ __launch_bounds__(128) void build_lists(
    const float* __restrict__ route, int* __restrict__ counts,
    int* __restrict__ list_b, float* __restrict__ list_p) {
  __shared__ float4 r_sh[B_];
  int t = threadIdx.x;  // 128
  r_sh[t] = *(const float4*)(route + (size_t)t * 8);  // router-0 entry of sample t
  __syncthreads();
  if (t < E_) {
    int c = 0;
    for (int b = 0; b < B_; ++b) {
      float4 r = r_sh[b];
      int i0 = __float_as_int(r.x);
      int i1 = __float_as_int(r.y);
      if (i0 == t)      { list_b[t * B_ + c] = b; list_p[t * B_ + c] = r.z; ++c; }
      else if (i1 == t) { list_b[t * B_ + c] = b; list_p[t * B_ + c] = r.w; ++c; }
    }
    counts[t] = c;
  }
}

// ---------------- Kernel B: bias init: out[b] = pb0*eb[ib0] + pb1*eb[ib1] --------
__global__ __launch_bounds__(256) void bias_init(
    const float* __restrict__ route, const float* __restrict__ eb,
    float* __restrict__ out) {
  int b = blockIdx.x;
  int t = threadIdx.x;
  const float* rp = route + ((size_t)b * 2 + 1) * 4;
  int ib0 = __float_as_int(rp[0]);
  int ib1 = __float_as_int(rp[1]);
  float pb0 = rp[2], pb1 = rp[3];
  float4 b0 = ((const float4*)(eb + (size_t)ib0 * OUT_))[t];
  float4 b1 = ((const float4*)(eb + (size_t)ib1 * OUT_))[t];
  float4 o;
  o.x = pb0 * b0.x + pb1 * b1.x;
  o.y = pb0 * b0.y + pb1 * b1.y;
  o.z = pb0 * b0.z + pb1 * b1.z;
  o.w = pb0 * b0.w + pb1 * b1.w;
  ((float4*)(out + (size_t)b * OUT_))[t] = o;
}

// ---------------- Kernel C: linear-streamed expert matvecs, reg-prefetched -------
// block = (e, slab of 64 i-rows). 512 threads: thread t owns output cols
// [2t, 2t+1] -> each thread directly consumes the weights it loads (no LDS
// redistribution). Weight stream is linear: batch of RB=4 rows prefetched
// into nxt[] while cur[] is consumed (4 independent dwordx2 loads in flight
// per thread). acc float2[16] fully static. __launch_bounds__(512,2) caps
// VGPR at 128; est. use ~85 -> no scratch.
__global__ __launch_bounds__(THR, 2) void moe_main(
    const float* __restrict__ x, const float* __restrict__ ew,
    const int* __restrict__ counts, const int* __restrict__ list_b,
    const float* __restrict__ list_p, float* __restrict__ out) {
  int e    = blockIdx.x;
  int slab = blockIdx.y;
  int c = counts[e];
  if (c == 0) return;

  __shared__ float xs[SLAB][S_];   // [i][s], rows 64B-aligned -> b128 broadcast reads
  __shared__ int   bs[S_];
  __shared__ float ps[S_];

  int t  = threadIdx.x;
  int i0 = slab * SLAB;
  const float* wslab = ew + ((size_t)e * IN_ + i0) * OUT_;

  for (int g0 = 0; g0 < c; g0 += S_) {
    __syncthreads();   // previous pass's bs/ps/xs readers done
    if (t < S_) {
      int idx = g0 + t;
      int cidx = min(idx, c - 1);
      bs[t] = list_b[e * B_ + cidx];
      ps[t] = (idx < c) ? list_p[e * B_ + cidx] : 0.f;
    }
    __syncthreads();

    // stage x transposed: thread t -> (s = t&15, i-pair = t>>4)
    {
      int s  = t & 15;
      int ip = t >> 4;                    // 0..31
      const float* xr = x + (size_t)bs[s] * IN_ + i0 + 2 * ip;
      float2 v = *(const float2*)xr;
      xs[2 * ip][s]     = v.x;
      xs[2 * ip + 1][s] = v.y;
    }
    __syncthreads();

    float2 acc[S_];
    #pragma unroll
    for (int s = 0; s < S_; ++s) acc[s] = make_float2(0.f, 0.f);

    // prologue: load batch 0 (4 independent dwordx2)
    float2 cur[RB];
    {
      const float* wp = wslab + 2 * t;
      #pragma unroll
      for (int r = 0; r < RB; ++r)
        cur[r] = *(const float2*)(wp + (size_t)r * OUT_);
    }

    #pragma unroll 2
    for (int ib = 0; ib < SLAB; ib += RB) {
      bool has_next = (ib + RB < SLAB);
      float2 nxt[RB];
      if (has_next) {
        const float* wp = wslab + (size_t)(ib + RB) * OUT_ + 2 * t;
        #pragma unroll
        for (int r = 0; r < RB; ++r)
          nxt[r] = *(const float2*)(wp + (size_t)r * OUT_);
      }

      // consume cur: rows ib..ib+3
      #pragma unroll
      for (int r = 0; r < RB; ++r) {
        const float4* xr = (const float4*)xs[ib + r];
        float4 xa = xr[0], xb = xr[1], xc = xr[2], xd = xr[3];
        float2 wv = cur[r];
        acc[0].x  += xa.x * wv.x;  acc[0].y  += xa.x * wv.y;
        acc[1].x  += xa.y * wv.x;  acc[1].y  += xa.y * wv.y;
        acc[2].x  += xa.z * wv.x;  acc[2].y  += xa.z * wv.y;
        acc[3].x  += xa.w * wv.x;  acc[3].y  += xa.w * wv.y;
        acc[4].x  += xb.x * wv.x;  acc[4].y  += xb.x * wv.y;
        acc[5].x  += xb.y * wv.x;  acc[5].y  += xb.y * wv.y;
        acc[6].x  += xb.z * wv.x;  acc[6].y  += xb.z * wv.y;
        acc[7].x  += xb.w * wv.x;  acc[7].y  += xb.w * wv.y;
        acc[8].x  += xc.x * wv.x;  acc[8].y  += xc.x * wv.y;
        acc[9].x  += xc.y * wv.x;  acc[9].y  += xc.y * wv.y;
        acc[10].x += xc.z * wv.x;  acc[10].y += xc.z * wv.y;
        acc[11].x += xc.w * wv.x;  acc[11].y += xc.w * wv.y;
        acc[12].x += xd.x * wv.x;  acc[12].y += xd.x * wv.y;
        acc[13].x += xd.y * wv.x;  acc[13].y += xd.y * wv.y;
        acc[14].x += xd.z * wv.x;  acc[14].y += xd.z * wv.y;
        acc[15].x += xd.w * wv.x;  acc[15].y += xd.w * wv.y;
      }

      if (has_next) {
        #pragma unroll
        for (int r = 0; r < RB; ++r) cur[r] = nxt[r];
      }
    }

    // epilogue: one atomic contribution per (sample, col pair) for this slab
    #pragma unroll
    for (int s = 0; s < S_; ++s) {
      if (g0 + s < c) {
        float p = ps[s];
        float* op = out + (size_t)bs[s] * OUT_ + 2 * t;
        atomicAdd(op + 0, p * acc[s].x);
        atomicAdd(op + 1, p * acc[s].y);
      }
    }
  }
}

extern "C" void kernel_launch(void* const* d_in, const int* in_sizes, int n_in,
                              void* d_out, int out_size, void* d_ws, size_t ws_size,
                              hipStream_t stream) {
  const float* x   = (const float*)d_in[0];
  const float* rw  = (const float*)d_in[1];
  const float* brw = (const float*)d_in[2];
  const float* ew  = (const float*)d_in[3];
  const float* eb  = (const float*)d_in[4];
  float* out = (float*)d_out;

  float* route  = (float*)d_ws;                                   // 128*2*4 floats = 4 KB
  int*   counts = (int*)((char*)d_ws + 4096);                     // 32 ints
  int*   list_b = (int*)((char*)d_ws + 4096 + 128);               // 32*128 ints
  float* list_p = (float*)((char*)d_ws + 4096 + 128 + 16384);     // 32*128 floats

  route_kernel<<<dim3(B_, 2), 256, 0, stream>>>(x, rw, brw, route);
  build_lists<<<1, 128, 0, stream>>>(route, counts, list_b, list_p);
  bias_init<<<B_, 256, 0, stream>>>(route, eb, out);
  moe_main<<<dim3(E_, NSLAB), THR, 0, stream>>>(x, ew, counts, list_b, list_p, out);
}